// Round 1
// baseline (485.164 us; speedup 1.0000x reference)
//
#include <hip/hip_runtime.h>
#include <math.h>

#define NB 16384
#define DIM 128
#define SUMK 4096
#define KCLS 2048

constexpr float LA = 20.0f;
constexpr float GAMMA_INV = 10.0f;
constexpr float TAU = 0.2f;
constexpr float MARGIN = 0.01f;
// N_PAIRS*2 = 2 * (2048*2047/2) * 2 = 2048*2047*2
constexpr float NPAIRS2 = 8384512.0f;

// ---------------------------------------------------------------------------
// Normalize centers: cn[d][j] = fc[d][j] / ||fc[:,j]||
// ---------------------------------------------------------------------------
__global__ __launch_bounds__(256) void knorm(const float* __restrict__ fc,
                                             float* __restrict__ cn) {
    int j = blockIdx.x * 256 + threadIdx.x;
    float ss = 0.f;
    for (int d = 0; d < DIM; ++d) {
        float v = fc[d * SUMK + j];
        ss = fmaf(v, v, ss);
    }
    float rn = 1.0f / sqrtf(ss);
    for (int d = 0; d < DIM; ++d)
        cn[d * SUMK + j] = fc[d * SUMK + j] * rn;
}

// ---------------------------------------------------------------------------
// Fused: normalize x rows, sim = xn @ cn (one class per block), online
// softmax-weighted reduction over the class's 2048 columns, emit logits.
// Block: 256 threads, 64 rows x 64-col chunks, K=128 in LDS.
// ---------------------------------------------------------------------------
__global__ __launch_bounds__(256) void kmain(const float* __restrict__ x,
                                             const float* __restrict__ cn,
                                             float* __restrict__ out) {
    __shared__ float x_s[DIM][64];  // x^T, normalized  (32 KB)
    __shared__ float c_s[DIM][64];  // centers tile     (32 KB)

    const int t = threadIdx.x;
    const int b0 = blockIdx.x * 64;
    const int cls = blockIdx.y;

    // ---- load x rows, compute row norms, store transposed normalized ----
    {
        const int r = t >> 2;      // 0..63 row
        const int q = t & 3;       // quarter of the 128-dim row
        const float4* xr = (const float4*)(x + (b0 + r) * DIM + q * 32);
        float ss = 0.f;
#pragma unroll
        for (int i = 0; i < 8; ++i) {
            float4 f = xr[i];
            ss = fmaf(f.x, f.x, ss); ss = fmaf(f.y, f.y, ss);
            ss = fmaf(f.z, f.z, ss); ss = fmaf(f.w, f.w, ss);
        }
        ss += __shfl_xor(ss, 1);
        ss += __shfl_xor(ss, 2);
        float rn = 1.0f / sqrtf(ss);
#pragma unroll
        for (int i = 0; i < 8; ++i) {
            float4 f = xr[i];
            int k = q * 32 + i * 4;
            x_s[k + 0][r] = f.x * rn;
            x_s[k + 1][r] = f.y * rn;
            x_s[k + 2][r] = f.z * rn;
            x_s[k + 3][r] = f.w * rn;
        }
    }

    const int tr = t >> 4;  // 0..15 -> rows tr*4..tr*4+3
    const int tc = t & 15;  // 0..15 -> cols tc*4..tc*4+3

    // running online-softmax state for this thread-group's 4 rows
    // (only meaningful in tc==0 lanes)
    float rm[4], rz[4], rw[4];
#pragma unroll
    for (int i = 0; i < 4; ++i) { rm[i] = -INFINITY; rz[i] = 0.f; rw[i] = 0.f; }

    for (int cc = 0; cc < KCLS / 64; ++cc) {
        const int j0 = cls * KCLS + cc * 64;
        // stage centers tile [128][64]
        {
            const int j4 = (t & 15) * 4;
            const int kk = t >> 4;
#pragma unroll
            for (int s = 0; s < 8; ++s) {
                int k = s * 16 + kk;
                *(float4*)&c_s[k][j4] = *(const float4*)&cn[k * SUMK + j0 + j4];
            }
        }
        __syncthreads();

        float acc[4][4];
#pragma unroll
        for (int i = 0; i < 4; ++i)
#pragma unroll
            for (int jj = 0; jj < 4; ++jj) acc[i][jj] = 0.f;

#pragma unroll 4
        for (int k = 0; k < DIM; ++k) {
            float4 av = *(const float4*)&x_s[k][tr * 4];
            float4 bv = *(const float4*)&c_s[k][tc * 4];
            float a4[4] = {av.x, av.y, av.z, av.w};
            float b4[4] = {bv.x, bv.y, bv.z, bv.w};
#pragma unroll
            for (int i = 0; i < 4; ++i)
#pragma unroll
                for (int jj = 0; jj < 4; ++jj)
                    acc[i][jj] = fmaf(a4[i], b4[jj], acc[i][jj]);
        }

        // per-thread partial softmax stats (4 cols) for each of the 4 rows
        float m4[4], z4[4], w4[4];
#pragma unroll
        for (int i = 0; i < 4; ++i) {
            float g0 = acc[i][0] * GAMMA_INV, g1 = acc[i][1] * GAMMA_INV;
            float g2 = acc[i][2] * GAMMA_INV, g3 = acc[i][3] * GAMMA_INV;
            float m = fmaxf(fmaxf(g0, g1), fmaxf(g2, g3));
            float e0 = expf(g0 - m), e1 = expf(g1 - m);
            float e2 = expf(g2 - m), e3 = expf(g3 - m);
            m4[i] = m;
            z4[i] = e0 + e1 + e2 + e3;
            w4[i] = e0 * acc[i][0] + e1 * acc[i][1] + e2 * acc[i][2] + e3 * acc[i][3];
        }
        // reduce across the 16 lanes (same wave) sharing these rows
#pragma unroll
        for (int off = 1; off < 16; off <<= 1) {
#pragma unroll
            for (int i = 0; i < 4; ++i) {
                float om = __shfl_xor(m4[i], off);
                float oz = __shfl_xor(z4[i], off);
                float ow = __shfl_xor(w4[i], off);
                float nm = fmaxf(m4[i], om);
                float ea = expf(m4[i] - nm), eb = expf(om - nm);
                z4[i] = z4[i] * ea + oz * eb;
                w4[i] = w4[i] * ea + ow * eb;
                m4[i] = nm;
            }
        }
        // merge chunk stats into running state
        if (tc == 0) {
#pragma unroll
            for (int i = 0; i < 4; ++i) {
                float nm = fmaxf(rm[i], m4[i]);
                float ea = expf(rm[i] - nm), eb = expf(m4[i] - nm);
                rz[i] = rz[i] * ea + z4[i] * eb;
                rw[i] = rw[i] * ea + w4[i] * eb;
                rm[i] = nm;
            }
        }
        __syncthreads();  // before next tile overwrites c_s
    }

    if (tc == 0) {
#pragma unroll
        for (int i = 0; i < 4; ++i) {
            int row = b0 + tr * 4 + i;
            float sc = rw[i] / rz[i];
            out[1 + row * 2 + cls] = LA * (sc - MARGIN);
        }
    }
}

// ---------------------------------------------------------------------------
// Cross-entropy over the 2 logits (reads logits from out), sum into accum.
// ---------------------------------------------------------------------------
__global__ __launch_bounds__(256) void kce(const float* __restrict__ out,
                                           const int* __restrict__ tgt,
                                           float* __restrict__ ce_acc) {
    int i = blockIdx.x * 256 + threadIdx.x;
    float l0 = out[1 + 2 * i];
    float l1 = out[2 + 2 * i];
    int tg = tgt[i];
    float mx = fmaxf(l0, l1);
    float lse = mx + logf(expf(l0 - mx) + expf(l1 - mx));
    float ce = lse - (tg ? l1 : l0);
#pragma unroll
    for (int off = 1; off < 64; off <<= 1) ce += __shfl_xor(ce, off);
    if ((threadIdx.x & 63) == 0) atomicAdd(ce_acc, ce);
}

// ---------------------------------------------------------------------------
// Center-pair regularizer: sum over intra-class i<j of sqrt(2+1e-5-2*c_i.c_j)
// 64x64 tiles over upper-triangular region of each class block.
// ---------------------------------------------------------------------------
__global__ __launch_bounds__(256) void kreg(const float* __restrict__ cn,
                                            float* __restrict__ reg_acc) {
    const int bid = blockIdx.x;
    const int cls = bid >> 10;
    const int ti = (bid >> 5) & 31;
    const int tj = bid & 31;
    if (tj < ti) return;

    __shared__ float a_s[DIM][64];
    __shared__ float b_s[DIM][64];
    const int t = threadIdx.x;
    const int i0 = cls * KCLS + ti * 64;
    const int j0 = cls * KCLS + tj * 64;
    {
        const int j4 = (t & 15) * 4;
        const int kk = t >> 4;
#pragma unroll
        for (int s = 0; s < 8; ++s) {
            int k = s * 16 + kk;
            *(float4*)&a_s[k][j4] = *(const float4*)&cn[k * SUMK + i0 + j4];
            *(float4*)&b_s[k][j4] = *(const float4*)&cn[k * SUMK + j0 + j4];
        }
    }
    __syncthreads();

    const int tr = t >> 4, tc = t & 15;
    float acc[4][4];
#pragma unroll
    for (int i = 0; i < 4; ++i)
#pragma unroll
        for (int jj = 0; jj < 4; ++jj) acc[i][jj] = 0.f;

#pragma unroll 4
    for (int k = 0; k < DIM; ++k) {
        float4 av = *(const float4*)&a_s[k][tr * 4];
        float4 bv = *(const float4*)&b_s[k][tc * 4];
        float a4[4] = {av.x, av.y, av.z, av.w};
        float b4[4] = {bv.x, bv.y, bv.z, bv.w};
#pragma unroll
        for (int i = 0; i < 4; ++i)
#pragma unroll
            for (int jj = 0; jj < 4; ++jj)
                acc[i][jj] = fmaf(a4[i], b4[jj], acc[i][jj]);
    }

    float local = 0.f;
#pragma unroll
    for (int i = 0; i < 4; ++i)
#pragma unroll
        for (int jj = 0; jj < 4; ++jj) {
            int gi = i0 + tr * 4 + i;
            int gj = j0 + tc * 4 + jj;
            if (gi < gj)
                local += sqrtf(fmaxf(2.0f + 1e-5f - 2.f * acc[i][jj], 0.f));
        }
#pragma unroll
    for (int off = 1; off < 64; off <<= 1) local += __shfl_xor(local, off);
    if ((t & 63) == 0) atomicAdd(reg_acc, local);
}

// ---------------------------------------------------------------------------
// Finalize loss
// ---------------------------------------------------------------------------
__global__ void kfin(const float* __restrict__ accum, float* __restrict__ out) {
    out[0] = accum[0] / (float)NB + TAU * (accum[1] / NPAIRS2);
}

extern "C" void kernel_launch(void* const* d_in, const int* in_sizes, int n_in,
                              void* d_out, int out_size, void* d_ws, size_t ws_size,
                              hipStream_t stream) {
    const float* x  = (const float*)d_in[0];
    const int*   tg = (const int*)d_in[1];
    const float* fc = (const float*)d_in[2];
    float* out = (float*)d_out;
    float* ws  = (float*)d_ws;
    float* accum = ws;         // [0]=ce sum, [1]=reg sum
    float* cn    = ws + 16;    // normalized centers, 128*4096 floats (2 MB)

    hipMemsetAsync(accum, 0, 64, stream);
    knorm<<<SUMK / 256, 256, 0, stream>>>(fc, cn);
    kmain<<<dim3(NB / 64, 2), 256, 0, stream>>>(x, cn, out);
    kce<<<NB / 256, 256, 0, stream>>>(out, tg, accum);
    kreg<<<2048, 256, 0, stream>>>(cn, accum + 1);
    kfin<<<1, 1, 0, stream>>>(accum, out);
}

// Round 2
// 253.046 us; speedup vs baseline: 1.9173x; 1.9173x over previous
//
#include <hip/hip_runtime.h>
#include <math.h>

#define NB 16384
#define DIM 128
#define SUMK 4096
#define KCLS 2048

constexpr float LA = 20.0f;
constexpr float GAMMA_INV = 10.0f;
constexpr float TAU = 0.2f;
constexpr float MARGIN = 0.01f;
constexpr float NPAIRS2 = 8384512.0f;          // 2048*2047*2
constexpr float G2L = 14.426950408889634f;     // GAMMA_INV * log2(e)

typedef _Float16 half8 __attribute__((ext_vector_type(8)));
typedef float f32x4 __attribute__((ext_vector_type(4)));

// ---------------------------------------------------------------------------
// Normalize centers, write fp16 transposed: cnT[j][d] = fc[d][j]/||fc[:,j]||
// ---------------------------------------------------------------------------
__global__ __launch_bounds__(256) void knorm(const float* __restrict__ fc,
                                             _Float16* __restrict__ cnT) {
    int j = blockIdx.x * 256 + threadIdx.x;
    float ss = 0.f;
    for (int d = 0; d < DIM; ++d) {
        float v = fc[d * SUMK + j];
        ss = fmaf(v, v, ss);
    }
    float rn = 1.0f / sqrtf(ss);
#pragma unroll
    for (int d8 = 0; d8 < 16; ++d8) {
        half8 h;
#pragma unroll
        for (int q = 0; q < 8; ++q)
            h[q] = (_Float16)(fc[(d8 * 8 + q) * SUMK + j] * rn);
        *(half8*)(cnT + (size_t)j * DIM + d8 * 8) = h;
    }
}

// ---------------------------------------------------------------------------
// Fused: normalize x rows -> fp16 B-fragments (registers), stream center
// A-fragments from global (L2-hot), MFMA, online softmax-weighted reduction.
// Wave = 16 rows x one class. No LDS, no barriers. Manual reg double-buffer.
// ---------------------------------------------------------------------------
__global__ __launch_bounds__(256) void kmain(const float* __restrict__ x,
                                             const _Float16* __restrict__ cnT,
                                             float* __restrict__ out) {
    const int t = threadIdx.x;
    const int lane = t & 63;
    const int wid = t >> 6;
    const int cls = blockIdx.y;
    const int rg = blockIdx.x * 4 + wid;   // 0..1023 row group (16 rows each)
    const int r0 = rg * 16;
    const int m = lane & 15;
    const int kg = lane >> 4;

    // ---- load 16 x rows, normalize, pack into B fragments ----
    float xr[4][8];
    const float* xp = x + (size_t)(r0 + m) * DIM + kg * 8;
    float ss = 0.f;
#pragma unroll
    for (int tt = 0; tt < 4; ++tt) {
        float4 f0 = *(const float4*)(xp + tt * 32);
        float4 f1 = *(const float4*)(xp + tt * 32 + 4);
        xr[tt][0] = f0.x; xr[tt][1] = f0.y; xr[tt][2] = f0.z; xr[tt][3] = f0.w;
        xr[tt][4] = f1.x; xr[tt][5] = f1.y; xr[tt][6] = f1.z; xr[tt][7] = f1.w;
#pragma unroll
        for (int q = 0; q < 8; ++q) ss = fmaf(xr[tt][q], xr[tt][q], ss);
    }
    ss += __shfl_xor(ss, 16);
    ss += __shfl_xor(ss, 32);
    float rn = 1.0f / sqrtf(ss);
    half8 bfrag[4];
#pragma unroll
    for (int tt = 0; tt < 4; ++tt)
#pragma unroll
        for (int q = 0; q < 8; ++q)
            bfrag[tt][q] = (_Float16)(xr[tt][q] * rn);

    // ---- stream center fragments: 64 chunks of 32 cols ----
    const _Float16* p0 = cnT + ((size_t)cls * KCLS + m) * DIM + kg * 8;
    const _Float16* p1 = p0 + 16 * DIM;
    const int STEP = 32 * DIM;

    half8 A0[2][4], A1[2][4];

#define LOADA(BUF, P0, P1)                                     \
    do {                                                       \
        _Pragma("unroll") for (int tt = 0; tt < 4; ++tt) {     \
            BUF[0][tt] = *(const half8*)((P0) + tt * 32);      \
            BUF[1][tt] = *(const half8*)((P1) + tt * 32);      \
        }                                                      \
    } while (0)

    float rm = -1e30f, rz = 0.f, rw = 0.f;

#define PROCESS(BUF)                                                          \
    do {                                                                      \
        f32x4 c0 = {0.f, 0.f, 0.f, 0.f}, c1 = {0.f, 0.f, 0.f, 0.f};          \
        _Pragma("unroll") for (int tt = 0; tt < 4; ++tt) {                    \
            c0 = __builtin_amdgcn_mfma_f32_16x16x32_f16(BUF[0][tt], bfrag[tt], c0, 0, 0, 0); \
            c1 = __builtin_amdgcn_mfma_f32_16x16x32_f16(BUF[1][tt], bfrag[tt], c1, 0, 0, 0); \
        }                                                                     \
        float s0 = c0[0], s1 = c0[1], s2 = c0[2], s3 = c0[3];                 \
        float s4 = c1[0], s5 = c1[1], s6 = c1[2], s7 = c1[3];                 \
        float mc = fmaxf(fmaxf(fmaxf(s0, s1), fmaxf(s2, s3)),                 \
                         fmaxf(fmaxf(s4, s5), fmaxf(s6, s7))) * G2L;          \
        float nm = fmaxf(rm, mc);                                             \
        float sc = exp2f(rm - nm);                                            \
        rz *= sc; rw *= sc;                                                   \
        float e;                                                              \
        e = exp2f(fmaf(s0, G2L, -nm)); rz += e; rw = fmaf(e, s0, rw);         \
        e = exp2f(fmaf(s1, G2L, -nm)); rz += e; rw = fmaf(e, s1, rw);         \
        e = exp2f(fmaf(s2, G2L, -nm)); rz += e; rw = fmaf(e, s2, rw);         \
        e = exp2f(fmaf(s3, G2L, -nm)); rz += e; rw = fmaf(e, s3, rw);         \
        e = exp2f(fmaf(s4, G2L, -nm)); rz += e; rw = fmaf(e, s4, rw);         \
        e = exp2f(fmaf(s5, G2L, -nm)); rz += e; rw = fmaf(e, s5, rw);         \
        e = exp2f(fmaf(s6, G2L, -nm)); rz += e; rw = fmaf(e, s6, rw);         \
        e = exp2f(fmaf(s7, G2L, -nm)); rz += e; rw = fmaf(e, s7, rw);         \
        rm = nm;                                                              \
    } while (0)

    LOADA(A0, p0, p1); p0 += STEP; p1 += STEP;
    for (int c2 = 0; c2 < 32; ++c2) {
        LOADA(A1, p0, p1); p0 += STEP; p1 += STEP;
        PROCESS(A0);
        if (c2 < 31) { LOADA(A0, p0, p1); p0 += STEP; p1 += STEP; }
        PROCESS(A1);
    }

    // merge the 4 k-groups (lanes m, m+16, m+32, m+48)
#pragma unroll
    for (int off = 16; off <= 32; off <<= 1) {
        float om = __shfl_xor(rm, off);
        float oz = __shfl_xor(rz, off);
        float ow = __shfl_xor(rw, off);
        float nm = fmaxf(rm, om);
        float ea = exp2f(rm - nm), eb = exp2f(om - nm);
        rz = rz * ea + oz * eb;
        rw = rw * ea + ow * eb;
        rm = nm;
    }
    if (lane < 16)
        out[1 + (size_t)(r0 + m) * 2 + cls] = LA * (rw / rz - MARGIN);
#undef LOADA
#undef PROCESS
}

// ---------------------------------------------------------------------------
// Cross-entropy over the 2 logits
// ---------------------------------------------------------------------------
__global__ __launch_bounds__(256) void kce(const float* __restrict__ out,
                                           const int* __restrict__ tgt,
                                           float* __restrict__ ce_acc) {
    int i = blockIdx.x * 256 + threadIdx.x;
    float l0 = out[1 + 2 * i];
    float l1 = out[2 + 2 * i];
    int tg = tgt[i];
    float mx = fmaxf(l0, l1);
    float lse = mx + logf(expf(l0 - mx) + expf(l1 - mx));
    float ce = lse - (tg ? l1 : l0);
#pragma unroll
    for (int off = 1; off < 64; off <<= 1) ce += __shfl_xor(ce, off);
    if ((threadIdx.x & 63) == 0) atomicAdd(ce_acc, ce);
}

// ---------------------------------------------------------------------------
// Center-pair regularizer via MFMA: intra-class i<j sqrt(2+1e-5-2*c_i.c_j)
// ---------------------------------------------------------------------------
__global__ __launch_bounds__(256) void kreg(const _Float16* __restrict__ cnT,
                                            float* __restrict__ reg_acc) {
    const int bid = blockIdx.x;
    const int cls = bid >> 10;
    const int ti = (bid >> 5) & 31;
    const int tj = bid & 31;
    if (tj < ti) return;

    const int t = threadIdx.x;
    const int lane = t & 63;
    const int wid = t >> 6;
    const int m = lane & 15;
    const int kg = lane >> 4;
    const int i0 = cls * KCLS + ti * 64 + wid * 16;
    const int jb = cls * KCLS + tj * 64;

    const _Float16* aip = cnT + (size_t)(i0 + m) * DIM + kg * 8;
    half8 af[4];
#pragma unroll
    for (int tt = 0; tt < 4; ++tt) af[tt] = *(const half8*)(aip + tt * 32);

    float local = 0.f;
#pragma unroll
    for (int fj = 0; fj < 4; ++fj) {
        const _Float16* bjp = cnT + (size_t)(jb + fj * 16 + m) * DIM + kg * 8;
        half8 bf[4];
#pragma unroll
        for (int tt = 0; tt < 4; ++tt) bf[tt] = *(const half8*)(bjp + tt * 32);
        f32x4 cc = {0.f, 0.f, 0.f, 0.f};
#pragma unroll
        for (int tt = 0; tt < 4; ++tt)
            cc = __builtin_amdgcn_mfma_f32_16x16x32_f16(af[tt], bf[tt], cc, 0, 0, 0);
        int gj = jb + fj * 16 + m;
#pragma unroll
        for (int r = 0; r < 4; ++r) {
            int gi = i0 + kg * 4 + r;
            if (gi < gj)
                local += sqrtf(fmaxf(2.0f + 1e-5f - 2.f * cc[r], 0.f));
        }
    }
#pragma unroll
    for (int off = 1; off < 64; off <<= 1) local += __shfl_xor(local, off);
    if (lane == 0) atomicAdd(reg_acc, local);
}

// ---------------------------------------------------------------------------
// Finalize loss
// ---------------------------------------------------------------------------
__global__ void kfin(const float* __restrict__ accum, float* __restrict__ out) {
    out[0] = accum[0] / (float)NB + TAU * (accum[1] / NPAIRS2);
}

extern "C" void kernel_launch(void* const* d_in, const int* in_sizes, int n_in,
                              void* d_out, int out_size, void* d_ws, size_t ws_size,
                              hipStream_t stream) {
    const float* x  = (const float*)d_in[0];
    const int*   tg = (const int*)d_in[1];
    const float* fc = (const float*)d_in[2];
    float* out = (float*)d_out;
    float* ws  = (float*)d_ws;
    float* accum = ws;                        // [0]=ce sum, [1]=reg sum
    _Float16* cnT = (_Float16*)(ws + 16);     // [SUMK][DIM] fp16, 1 MB

    hipMemsetAsync(accum, 0, 64, stream);
    knorm<<<SUMK / 256, 256, 0, stream>>>(fc, cnT);
    kmain<<<dim3(NB / 64, 2), 256, 0, stream>>>(x, cnT, out);
    kce<<<NB / 256, 256, 0, stream>>>(out, tg, accum);
    kreg<<<2048, 256, 0, stream>>>(cnT, accum + 1);
    kfin<<<1, 1, 0, stream>>>(accum, out);
}

// Round 4
// 199.807 us; speedup vs baseline: 2.4282x; 1.2665x over previous
//
#include <hip/hip_runtime.h>
#include <math.h>

#define NB 16384
#define DIM 128
#define SUMK 4096
#define KCLS 2048
#define QCOLS 512   // center columns per wave (one class quarter)

constexpr float LA = 20.0f;
constexpr float GAMMA_INV = 10.0f;
constexpr float TAU = 0.2f;
constexpr float MARGIN = 0.01f;
constexpr float NPAIRS2 = 8384512.0f;          // 2048*2047*2
constexpr float G2L = 14.426950408889634f;     // GAMMA_INV * log2(e)
#define CS (8 * NB)                            // per-component stride in pw

typedef _Float16 half8 __attribute__((ext_vector_type(8)));
typedef float f32x4 __attribute__((ext_vector_type(4)));

// ---------------------------------------------------------------------------
// Normalize centers, write fp16 transposed: cnT[j][d] = fc[d][j]/||fc[:,j]||
// 64 blocks; warp = 16 columns, 4 lanes per column (one d-quarter each).
// ---------------------------------------------------------------------------
__global__ __launch_bounds__(256) void knorm(const float* __restrict__ fc,
                                             _Float16* __restrict__ cnT) {
    const int t = threadIdx.x;
    const int lane = t & 63;
    const int wid = t >> 6;
    const int c = lane & 15;
    const int q = lane >> 4;
    const int j = blockIdx.x * 64 + wid * 16 + c;

    float v[32];
    const float* p = fc + (size_t)(q * 32) * SUMK + j;
    float ss = 0.f;
#pragma unroll
    for (int i = 0; i < 32; ++i) {
        v[i] = p[(size_t)i * SUMK];
        ss = fmaf(v[i], v[i], ss);
    }
    ss += __shfl_xor(ss, 16);
    ss += __shfl_xor(ss, 32);
    float rn = 1.0f / sqrtf(ss);

    _Float16* w = cnT + (size_t)j * DIM + q * 32;
#pragma unroll
    for (int s = 0; s < 4; ++s) {
        half8 h;
#pragma unroll
        for (int k = 0; k < 8; ++k) h[k] = (_Float16)(v[s * 8 + k] * rn);
        *(half8*)(w + s * 8) = h;
    }
}

// ---------------------------------------------------------------------------
// Fused GEMM + online softmax-weighted reduction, partial per column-quarter.
// Wave = 32 x-rows x 512 center cols. Grid (128,2,4): 4096 waves, 16/CU.
// Register ping-pong double-buffer on center A-fragments (16-col chunks).
// ---------------------------------------------------------------------------
__global__ __launch_bounds__(256, 4) void kmain(const float* __restrict__ x,
                                                const _Float16* __restrict__ cnT,
                                                float* __restrict__ pw) {
    const int t = threadIdx.x;
    const int lane = t & 63;
    const int wid = t >> 6;
    const int m = lane & 15;
    const int kg = lane >> 4;
    const int cls = blockIdx.y;
    const int qz = blockIdx.z;
    const int r0 = blockIdx.x * 128 + wid * 32;

    // ---- load + normalize 2 x-rows into B fragments ----
    half8 b0[4], b1[4];
#define LOADX(ROW, BF)                                                        \
    do {                                                                      \
        const float* xp = x + (size_t)(ROW)*DIM + kg * 8;                     \
        float xr[4][8];                                                       \
        float ss = 0.f;                                                       \
        _Pragma("unroll") for (int tt = 0; tt < 4; ++tt) {                    \
            float4 f0 = *(const float4*)(xp + tt * 32);                       \
            float4 f1 = *(const float4*)(xp + tt * 32 + 4);                   \
            xr[tt][0] = f0.x; xr[tt][1] = f0.y; xr[tt][2] = f0.z;             \
            xr[tt][3] = f0.w; xr[tt][4] = f1.x; xr[tt][5] = f1.y;             \
            xr[tt][6] = f1.z; xr[tt][7] = f1.w;                               \
            _Pragma("unroll") for (int qq = 0; qq < 8; ++qq)                  \
                ss = fmaf(xr[tt][qq], xr[tt][qq], ss);                        \
        }                                                                     \
        ss += __shfl_xor(ss, 16);                                             \
        ss += __shfl_xor(ss, 32);                                             \
        float rn = 1.0f / sqrtf(ss);                                          \
        _Pragma("unroll") for (int tt = 0; tt < 4; ++tt)                      \
            _Pragma("unroll") for (int qq = 0; qq < 8; ++qq)                  \
                BF[tt][qq] = (_Float16)(xr[tt][qq] * rn);                     \
    } while (0)

    LOADX(r0 + m, b0);
    LOADX(r0 + 16 + m, b1);
#undef LOADX

    // ---- stream centers: 32 chunks of 16 cols, reg ping-pong ----
    const _Float16* p = cnT + ((size_t)(cls * KCLS + qz * QCOLS) + m) * DIM + kg * 8;
    const int STEP = 16 * DIM;
    half8 A0_[4], A1_[4];

#define LOADA(BUF, P)                                                         \
    do {                                                                      \
        _Pragma("unroll") for (int tt = 0; tt < 4; ++tt)                      \
            BUF[tt] = *(const half8*)((P) + tt * 32);                         \
    } while (0)

    float rm0 = -1e30f, rz0 = 0.f, rw0 = 0.f;
    float rm1 = -1e30f, rz1 = 0.f, rw1 = 0.f;

#define EPI(C, RM, RZ, RW)                                                    \
    do {                                                                      \
        float mc = fmaxf(fmaxf(C[0], C[1]), fmaxf(C[2], C[3])) * G2L;         \
        float nm = fmaxf(RM, mc);                                             \
        float sc = exp2f(RM - nm);                                            \
        float e0 = exp2f(fmaf(C[0], G2L, -nm));                               \
        float e1 = exp2f(fmaf(C[1], G2L, -nm));                               \
        float e2 = exp2f(fmaf(C[2], G2L, -nm));                               \
        float e3 = exp2f(fmaf(C[3], G2L, -nm));                               \
        RZ = fmaf(RZ, sc, (e0 + e1) + (e2 + e3));                             \
        RW = fmaf(RW, sc, fmaf(e0, C[0], e1 * C[1]) + fmaf(e2, C[2], e3 * C[3])); \
        RM = nm;                                                              \
    } while (0)

#define PROCESS(BUF)                                                          \
    do {                                                                      \
        f32x4 c0 = {0.f, 0.f, 0.f, 0.f}, c1 = {0.f, 0.f, 0.f, 0.f};          \
        _Pragma("unroll") for (int tt = 0; tt < 4; ++tt) {                    \
            c0 = __builtin_amdgcn_mfma_f32_16x16x32_f16(BUF[tt], b0[tt], c0, 0, 0, 0); \
            c1 = __builtin_amdgcn_mfma_f32_16x16x32_f16(BUF[tt], b1[tt], c1, 0, 0, 0); \
        }                                                                     \
        EPI(c0, rm0, rz0, rw0);                                               \
        EPI(c1, rm1, rz1, rw1);                                               \
    } while (0)

    LOADA(A0_, p); p += STEP;
    for (int it = 0; it < 16; ++it) {
        LOADA(A1_, p); p += STEP;
        PROCESS(A0_);
        if (it < 15) { LOADA(A0_, p); p += STEP; }
        PROCESS(A1_);
    }
#undef LOADA
#undef PROCESS
#undef EPI

    // merge the 4 kg-groups (disjoint center subsets for the same x-row)
#pragma unroll
    for (int off = 16; off <= 32; off <<= 1) {
        {
            float om = __shfl_xor(rm0, off), oz = __shfl_xor(rz0, off), ow = __shfl_xor(rw0, off);
            float nm = fmaxf(rm0, om);
            float ea = exp2f(rm0 - nm), eb = exp2f(om - nm);
            rz0 = rz0 * ea + oz * eb; rw0 = rw0 * ea + ow * eb; rm0 = nm;
        }
        {
            float om = __shfl_xor(rm1, off), oz = __shfl_xor(rz1, off), ow = __shfl_xor(rw1, off);
            float nm = fmaxf(rm1, om);
            float ea = exp2f(rm1 - nm), eb = exp2f(om - nm);
            rz1 = rz1 * ea + oz * eb; rw1 = rw1 * ea + ow * eb; rm1 = nm;
        }
    }

    if (lane < 16) {
        const size_t base = (size_t)(cls * 4 + qz) * NB;
        const int rowA = r0 + m, rowB = r0 + 16 + m;
        pw[0 * CS + base + rowA] = rm0;
        pw[0 * CS + base + rowB] = rm1;
        pw[1 * CS + base + rowA] = rz0;
        pw[1 * CS + base + rowB] = rz1;
        pw[2 * CS + base + rowA] = rw0;
        pw[2 * CS + base + rowB] = rw1;
    }
}

// ---------------------------------------------------------------------------
// Merge column-quarter partials -> logits -> cross-entropy
// ---------------------------------------------------------------------------
__global__ __launch_bounds__(256) void kce(const float* __restrict__ pw,
                                           const int* __restrict__ tgt,
                                           float* __restrict__ out,
                                           float* __restrict__ ce_acc) {
    int i = blockIdx.x * 256 + threadIdx.x;
    float lg[2];
#pragma unroll
    for (int cls = 0; cls < 2; ++cls) {
        float nm = -1e30f, z = 0.f, w = 0.f;
#pragma unroll
        for (int q = 0; q < 4; ++q) {
            const size_t base = (size_t)(cls * 4 + q) * NB + i;
            float mq = pw[0 * CS + base];
            float zq = pw[1 * CS + base];
            float wq = pw[2 * CS + base];
            float n2 = fmaxf(nm, mq);
            float sa = exp2f(nm - n2), sb = exp2f(mq - n2);
            z = z * sa + zq * sb;
            w = w * sa + wq * sb;
            nm = n2;
        }
        lg[cls] = LA * (w / z - MARGIN);
        out[1 + 2 * i + cls] = lg[cls];
    }
    int tg = tgt[i];
    float mx = fmaxf(lg[0], lg[1]);
    float lse = mx + logf(expf(lg[0] - mx) + expf(lg[1] - mx));
    float ce = lse - (tg ? lg[1] : lg[0]);
#pragma unroll
    for (int off = 1; off < 64; off <<= 1) ce += __shfl_xor(ce, off);
    if ((threadIdx.x & 63) == 0) atomicAdd(ce_acc, ce);
}

// ---------------------------------------------------------------------------
// Center-pair regularizer via MFMA: intra-class i<j sqrt(2+1e-5-2*c_i.c_j)
// ---------------------------------------------------------------------------
__global__ __launch_bounds__(256) void kreg(const _Float16* __restrict__ cnT,
                                            float* __restrict__ reg_acc) {
    const int bid = blockIdx.x;
    const int cls = bid >> 10;
    const int ti = (bid >> 5) & 31;
    const int tj = bid & 31;
    if (tj < ti) return;

    const int t = threadIdx.x;
    const int lane = t & 63;
    const int wid = t >> 6;
    const int m = lane & 15;
    const int kg = lane >> 4;
    const int i0 = cls * KCLS + ti * 64 + wid * 16;
    const int jb = cls * KCLS + tj * 64;

    const _Float16* aip = cnT + (size_t)(i0 + m) * DIM + kg * 8;
    half8 af[4];
#pragma unroll
    for (int tt = 0; tt < 4; ++tt) af[tt] = *(const half8*)(aip + tt * 32);

    float local = 0.f;
#pragma unroll
    for (int fj = 0; fj < 4; ++fj) {
        const _Float16* bjp = cnT + (size_t)(jb + fj * 16 + m) * DIM + kg * 8;
        half8 bf[4];
#pragma unroll
        for (int tt = 0; tt < 4; ++tt) bf[tt] = *(const half8*)(bjp + tt * 32);
        f32x4 cc = {0.f, 0.f, 0.f, 0.f};
#pragma unroll
        for (int tt = 0; tt < 4; ++tt)
            cc = __builtin_amdgcn_mfma_f32_16x16x32_f16(af[tt], bf[tt], cc, 0, 0, 0);
        int gj = jb + fj * 16 + m;
#pragma unroll
        for (int r = 0; r < 4; ++r) {
            int gi = i0 + kg * 4 + r;
            if (gi < gj)
                local += sqrtf(fmaxf(2.0f + 1e-5f - 2.f * cc[r], 0.f));
        }
    }
#pragma unroll
    for (int off = 1; off < 64; off <<= 1) local += __shfl_xor(local, off);
    if (lane == 0) atomicAdd(reg_acc, local);
}

// ---------------------------------------------------------------------------
// Finalize loss
// ---------------------------------------------------------------------------
__global__ void kfin(const float* __restrict__ accum, float* __restrict__ out) {
    out[0] = accum[0] / (float)NB + TAU * (accum[1] / NPAIRS2);
}

extern "C" void kernel_launch(void* const* d_in, const int* in_sizes, int n_in,
                              void* d_out, int out_size, void* d_ws, size_t ws_size,
                              hipStream_t stream) {
    const float* x  = (const float*)d_in[0];
    const int*   tg = (const int*)d_in[1];
    const float* fc = (const float*)d_in[2];
    float* out = (float*)d_out;
    float* ws  = (float*)d_ws;
    float* accum = ws;                            // [0]=ce sum, [1]=reg sum
    _Float16* cnT = (_Float16*)(ws + 16);         // [SUMK][DIM] fp16, 1 MB
    float* pw = (float*)(cnT + (size_t)SUMK * DIM);  // partials, 3*8*NB floats

    hipMemsetAsync(accum, 0, 64, stream);
    knorm<<<SUMK / 64, 256, 0, stream>>>(fc, cnT);
    kmain<<<dim3(NB / 128, 2, 4), 256, 0, stream>>>(x, cnT, pw);
    kce<<<NB / 256, 256, 0, stream>>>(pw, tg, out, accum);
    kreg<<<2048, 256, 0, stream>>>(cnT, accum + 1);
    kfin<<<1, 1, 0, stream>>>(accum, out);
}

// Round 5
// 133.412 us; speedup vs baseline: 3.6366x; 1.4977x over previous
//
#include <hip/hip_runtime.h>
#include <math.h>

#define NB 16384
#define DIM 128
#define SUMK 4096
#define KCLS 2048

constexpr float LA = 20.0f;
constexpr float GAMMA_INV = 10.0f;
constexpr float TAU = 0.2f;
constexpr float MARGIN = 0.01f;
constexpr float NPAIRS2 = 8384512.0f;          // 2048*2047*2
constexpr float G2L = 14.426950408889634f;     // GAMMA_INV * log2(e)
#define CS (8 * NB)                            // per-component stride in pw

typedef _Float16 half8 __attribute__((ext_vector_type(8)));
typedef float f32x4 __attribute__((ext_vector_type(4)));

// direct global->LDS DMA, 16B per lane; dst is wave-uniform base (+lane*16 in HW)
#define GLOAD_LDS(SRC, DST)                                                          \
    __builtin_amdgcn_global_load_lds(                                                \
        (const __attribute__((address_space(1))) void*)(SRC),                        \
        (__attribute__((address_space(3))) void*)(DST), 16, 0, 0)

// ---------------------------------------------------------------------------
// Normalize centers, write fp16 transposed: cnT[j][d] = fc[d][j]/||fc[:,j]||
// ---------------------------------------------------------------------------
__global__ __launch_bounds__(256) void knorm(const float* __restrict__ fc,
                                             _Float16* __restrict__ cnT) {
    const int t = threadIdx.x;
    const int lane = t & 63;
    const int wid = t >> 6;
    const int c = lane & 15;
    const int q = lane >> 4;
    const int j = blockIdx.x * 64 + wid * 16 + c;

    float v[32];
    const float* p = fc + (size_t)(q * 32) * SUMK + j;
    float ss = 0.f;
#pragma unroll
    for (int i = 0; i < 32; ++i) {
        v[i] = p[(size_t)i * SUMK];
        ss = fmaf(v[i], v[i], ss);
    }
    ss += __shfl_xor(ss, 16);
    ss += __shfl_xor(ss, 32);
    float rn = 1.0f / sqrtf(ss);

    _Float16* w = cnT + (size_t)j * DIM + q * 32;
#pragma unroll
    for (int s = 0; s < 4; ++s) {
        half8 h;
#pragma unroll
        for (int k = 0; k < 8; ++k) h[k] = (_Float16)(v[s * 8 + k] * rn);
        *(half8*)(w + s * 8) = h;
    }
}

// ---------------------------------------------------------------------------
// kmain: fused GEMM + online softmax-weighted reduce.
// Block = 4 waves x 32 rows = 128 rows; 512 center cols (one class-quarter).
// Centers staged to LDS via global_load_lds in fragment-major layout
// (lane-linear -> conflict-free ds_read_b128), 32-col chunks, triple buffer,
// one barrier per chunk: stage(ch+2) latency hides under compute(ch).
// ---------------------------------------------------------------------------
__global__ __launch_bounds__(256, 4) void kmain(const float* __restrict__ x,
                                                const _Float16* __restrict__ cnT,
                                                float* __restrict__ pw) {
    __shared__ _Float16 smem[3][2][4][64][8];   // [buf][cf][tt][lane][8h] = 24 KB

    const int t = threadIdx.x;
    const int lane = t & 63;
    const int wid = t >> 6;
    const int m = lane & 15;
    const int kg = lane >> 4;
    const int cls = blockIdx.y;
    const int qz = blockIdx.z;
    const int r0 = blockIdx.x * 128 + wid * 32;

    // stage assignment: wave wid stages fragment-slices q = wid*2, wid*2+1
    // slice q covers (cf = q>>2, tt = q&3): cols cf*16+m, dims tt*32+kg*8..+8
    const int q0 = wid * 2, q1 = wid * 2 + 1;
    const int cf0 = q0 >> 2, tt0 = q0 & 3;
    const int cf1 = q1 >> 2, tt1 = q1 & 3;
    const int colbase = cls * KCLS + qz * 512;
    const _Float16* s0 = cnT + (size_t)(colbase + cf0 * 16 + m) * DIM + tt0 * 32 + kg * 8;
    const _Float16* s1 = cnT + (size_t)(colbase + cf1 * 16 + m) * DIM + tt1 * 32 + kg * 8;
    const size_t CSTEP = (size_t)32 * DIM;      // 32 columns of halves

#define STAGE(CH, BUF)                                            \
    do {                                                          \
        GLOAD_LDS(s0 + (size_t)(CH) * CSTEP, &smem[BUF][cf0][tt0][0][0]); \
        GLOAD_LDS(s1 + (size_t)(CH) * CSTEP, &smem[BUF][cf1][tt1][0][0]); \
    } while (0)

    STAGE(0, 0);
    STAGE(1, 1);

    // ---- load + normalize 2 x-rows into B fragments (overlaps staging) ----
    half8 b0[4], b1[4];
#define LOADX(ROW, BF)                                                        \
    do {                                                                      \
        const float* xp = x + (size_t)(ROW)*DIM + kg * 8;                     \
        float xr[4][8];                                                       \
        float ss = 0.f;                                                       \
        _Pragma("unroll") for (int tt = 0; tt < 4; ++tt) {                    \
            float4 f0 = *(const float4*)(xp + tt * 32);                       \
            float4 f1 = *(const float4*)(xp + tt * 32 + 4);                   \
            xr[tt][0] = f0.x; xr[tt][1] = f0.y; xr[tt][2] = f0.z;             \
            xr[tt][3] = f0.w; xr[tt][4] = f1.x; xr[tt][5] = f1.y;             \
            xr[tt][6] = f1.z; xr[tt][7] = f1.w;                               \
            _Pragma("unroll") for (int qq = 0; qq < 8; ++qq)                  \
                ss = fmaf(xr[tt][qq], xr[tt][qq], ss);                        \
        }                                                                     \
        ss += __shfl_xor(ss, 16);                                             \
        ss += __shfl_xor(ss, 32);                                             \
        float rn = 1.0f / sqrtf(ss);                                          \
        _Pragma("unroll") for (int tt = 0; tt < 4; ++tt)                      \
            _Pragma("unroll") for (int qq = 0; qq < 8; ++qq)                  \
                BF[tt][qq] = (_Float16)(xr[tt][qq] * rn);                     \
    } while (0)

    LOADX(r0 + m, b0);
    LOADX(r0 + 16 + m, b1);
#undef LOADX

    float rm0 = -1e30f, rz0 = 0.f, rw0 = 0.f;
    float rm1 = -1e30f, rz1 = 0.f, rw1 = 0.f;

#define EPI(C, RM, RZ, RW)                                                    \
    do {                                                                      \
        float mc = fmaxf(fmaxf(C[0], C[1]), fmaxf(C[2], C[3])) * G2L;         \
        float nm = fmaxf(RM, mc);                                             \
        float sc = exp2f(RM - nm);                                            \
        float e0 = exp2f(fmaf(C[0], G2L, -nm));                               \
        float e1 = exp2f(fmaf(C[1], G2L, -nm));                               \
        float e2 = exp2f(fmaf(C[2], G2L, -nm));                               \
        float e3 = exp2f(fmaf(C[3], G2L, -nm));                               \
        RZ = fmaf(RZ, sc, (e0 + e1) + (e2 + e3));                             \
        RW = fmaf(RW, sc, fmaf(e0, C[0], e1 * C[1]) + fmaf(e2, C[2], e3 * C[3])); \
        RM = nm;                                                              \
    } while (0)

    // ---- main loop: 16 chunks of 32 cols ----
    for (int ch = 0; ch < 16; ++ch) {
        __syncthreads();                         // buf[ch%3] staged & visible
        if (ch + 2 < 16) STAGE(ch + 2, (ch + 2) % 3);
        const int b = ch % 3;
#pragma unroll
        for (int cf = 0; cf < 2; ++cf) {
            half8 a0 = *(const half8*)&smem[b][cf][0][lane][0];
            half8 a1 = *(const half8*)&smem[b][cf][1][lane][0];
            half8 a2 = *(const half8*)&smem[b][cf][2][lane][0];
            half8 a3 = *(const half8*)&smem[b][cf][3][lane][0];
            f32x4 c0 = {0.f, 0.f, 0.f, 0.f}, c1 = {0.f, 0.f, 0.f, 0.f};
            c0 = __builtin_amdgcn_mfma_f32_16x16x32_f16(a0, b0[0], c0, 0, 0, 0);
            c1 = __builtin_amdgcn_mfma_f32_16x16x32_f16(a0, b1[0], c1, 0, 0, 0);
            c0 = __builtin_amdgcn_mfma_f32_16x16x32_f16(a1, b0[1], c0, 0, 0, 0);
            c1 = __builtin_amdgcn_mfma_f32_16x16x32_f16(a1, b1[1], c1, 0, 0, 0);
            c0 = __builtin_amdgcn_mfma_f32_16x16x32_f16(a2, b0[2], c0, 0, 0, 0);
            c1 = __builtin_amdgcn_mfma_f32_16x16x32_f16(a2, b1[2], c1, 0, 0, 0);
            c0 = __builtin_amdgcn_mfma_f32_16x16x32_f16(a3, b0[3], c0, 0, 0, 0);
            c1 = __builtin_amdgcn_mfma_f32_16x16x32_f16(a3, b1[3], c1, 0, 0, 0);
            EPI(c0, rm0, rz0, rw0);
            EPI(c1, rm1, rz1, rw1);
        }
    }
#undef EPI
#undef STAGE

    // merge the 4 kg-groups (disjoint center subsets for the same x-row)
#pragma unroll
    for (int off = 16; off <= 32; off <<= 1) {
        {
            float om = __shfl_xor(rm0, off), oz = __shfl_xor(rz0, off), ow = __shfl_xor(rw0, off);
            float nm = fmaxf(rm0, om);
            float ea = exp2f(rm0 - nm), eb = exp2f(om - nm);
            rz0 = rz0 * ea + oz * eb; rw0 = rw0 * ea + ow * eb; rm0 = nm;
        }
        {
            float om = __shfl_xor(rm1, off), oz = __shfl_xor(rz1, off), ow = __shfl_xor(rw1, off);
            float nm = fmaxf(rm1, om);
            float ea = exp2f(rm1 - nm), eb = exp2f(om - nm);
            rz1 = rz1 * ea + oz * eb; rw1 = rw1 * ea + ow * eb; rm1 = nm;
        }
    }

    if (lane < 16) {
        const size_t base = (size_t)(cls * 4 + qz) * NB;
        const int rowA = r0 + m, rowB = r0 + 16 + m;
        pw[0 * CS + base + rowA] = rm0;
        pw[0 * CS + base + rowB] = rm1;
        pw[1 * CS + base + rowA] = rz0;
        pw[1 * CS + base + rowB] = rz1;
        pw[2 * CS + base + rowA] = rw0;
        pw[2 * CS + base + rowB] = rw1;
    }
}

// ---------------------------------------------------------------------------
// Merge column-quarter partials -> logits -> cross-entropy
// ---------------------------------------------------------------------------
__global__ __launch_bounds__(256) void kce(const float* __restrict__ pw,
                                           const int* __restrict__ tgt,
                                           float* __restrict__ out,
                                           float* __restrict__ ce_acc) {
    int i = blockIdx.x * 256 + threadIdx.x;
    float lg[2];
#pragma unroll
    for (int cls = 0; cls < 2; ++cls) {
        float nm = -1e30f, z = 0.f, w = 0.f;
#pragma unroll
        for (int q = 0; q < 4; ++q) {
            const size_t base = (size_t)(cls * 4 + q) * NB + i;
            float mq = pw[0 * CS + base];
            float zq = pw[1 * CS + base];
            float wq = pw[2 * CS + base];
            float n2 = fmaxf(nm, mq);
            float sa = exp2f(nm - n2), sb = exp2f(mq - n2);
            z = z * sa + zq * sb;
            w = w * sa + wq * sb;
            nm = n2;
        }
        lg[cls] = LA * (w / z - MARGIN);
        out[1 + 2 * i + cls] = lg[cls];
    }
    int tg = tgt[i];
    float mx = fmaxf(lg[0], lg[1]);
    float lse = mx + logf(expf(lg[0] - mx) + expf(lg[1] - mx));
    float ce = lse - (tg ? lg[1] : lg[0]);
#pragma unroll
    for (int off = 1; off < 64; off <<= 1) ce += __shfl_xor(ce, off);
    if ((threadIdx.x & 63) == 0) atomicAdd(ce_acc, ce);
}

// ---------------------------------------------------------------------------
// Center-pair regularizer via MFMA. All 20 fragment loads issued upfront
// (one latency), block-level LDS reduce -> one atomic per block.
// ---------------------------------------------------------------------------
__global__ __launch_bounds__(256) void kreg(const _Float16* __restrict__ cnT,
                                            float* __restrict__ reg_acc) {
    const int bid = blockIdx.x;
    const int cls = bid >> 10;
    const int ti = (bid >> 5) & 31;
    const int tj = bid & 31;
    if (tj < ti) return;

    __shared__ float red[4];
    const int t = threadIdx.x;
    const int lane = t & 63;
    const int wid = t >> 6;
    const int m = lane & 15;
    const int kg = lane >> 4;
    const int i0 = cls * KCLS + ti * 64 + wid * 16;
    const int jb = cls * KCLS + tj * 64;

    // all loads upfront, independent -> single memory latency
    const _Float16* aip = cnT + (size_t)(i0 + m) * DIM + kg * 8;
    half8 af[4];
#pragma unroll
    for (int tt = 0; tt < 4; ++tt) af[tt] = *(const half8*)(aip + tt * 32);

    half8 bf[16];
#pragma unroll
    for (int fj = 0; fj < 4; ++fj) {
        const _Float16* bjp = cnT + (size_t)(jb + fj * 16 + m) * DIM + kg * 8;
#pragma unroll
        for (int tt = 0; tt < 4; ++tt) bf[fj * 4 + tt] = *(const half8*)(bjp + tt * 32);
    }

    float local = 0.f;
#pragma unroll
    for (int fj = 0; fj < 4; ++fj) {
        f32x4 cc = {0.f, 0.f, 0.f, 0.f};
#pragma unroll
        for (int tt = 0; tt < 4; ++tt)
            cc = __builtin_amdgcn_mfma_f32_16x16x32_f16(af[tt], bf[fj * 4 + tt], cc, 0, 0, 0);
        int gj = jb + fj * 16 + m;
#pragma unroll
        for (int r = 0; r < 4; ++r) {
            int gi = i0 + kg * 4 + r;
            if (gi < gj)
                local += sqrtf(fmaxf(2.0f + 1e-5f - 2.f * cc[r], 0.f));
        }
    }
#pragma unroll
    for (int off = 1; off < 64; off <<= 1) local += __shfl_xor(local, off);
    if (lane == 0) red[wid] = local;
    __syncthreads();
    if (t == 0) atomicAdd(reg_acc, (red[0] + red[1]) + (red[2] + red[3]));
}

// ---------------------------------------------------------------------------
// Finalize loss
// ---------------------------------------------------------------------------
__global__ void kfin(const float* __restrict__ accum, float* __restrict__ out) {
    out[0] = accum[0] / (float)NB + TAU * (accum[1] / NPAIRS2);
}

extern "C" void kernel_launch(void* const* d_in, const int* in_sizes, int n_in,
                              void* d_out, int out_size, void* d_ws, size_t ws_size,
                              hipStream_t stream) {
    const float* x  = (const float*)d_in[0];
    const int*   tg = (const int*)d_in[1];
    const float* fc = (const float*)d_in[2];
    float* out = (float*)d_out;
    float* ws  = (float*)d_ws;
    float* accum = ws;                            // [0]=ce sum, [1]=reg sum
    _Float16* cnT = (_Float16*)(ws + 16);         // [SUMK][DIM] fp16, 1 MB
    float* pw = (float*)(cnT + (size_t)SUMK * DIM);  // partials, 3*8*NB floats

    hipMemsetAsync(accum, 0, 64, stream);
    knorm<<<SUMK / 64, 256, 0, stream>>>(fc, cnT);
    kmain<<<dim3(NB / 128, 2, 4), 256, 0, stream>>>(x, cnT, pw);
    kreg<<<2048, 256, 0, stream>>>(cnT, accum + 1);
    kce<<<NB / 256, 256, 0, stream>>>(pw, tg, out, accum);
    kfin<<<1, 1, 0, stream>>>(accum, out);
}

// Round 6
// 117.649 us; speedup vs baseline: 4.1238x; 1.1340x over previous
//
#include <hip/hip_runtime.h>
#include <math.h>

#define NB 16384
#define DIM 128
#define SUMK 4096
#define KCLS 2048

constexpr float LA = 20.0f;
constexpr float TAU = 0.2f;
constexpr float MARGIN = 0.01f;
constexpr float NPAIRS2 = 8384512.0f;          // 2048*2047*2
constexpr float G2L = 14.426950408889634f;     // GAMMA_INV * log2(e)
#define CS (8 * NB)                            // per-component stride in pw

typedef _Float16 half8 __attribute__((ext_vector_type(8)));
typedef float f32x4 __attribute__((ext_vector_type(4)));

#if __has_builtin(__builtin_amdgcn_exp2f)
#define EXP2(v) __builtin_amdgcn_exp2f(v)
#else
#define EXP2(v) exp2f(v)
#endif

// direct global->LDS DMA, 16B per lane; dst is wave-uniform base (+lane*16 in HW)
#define GLOAD_LDS(SRC, DST)                                                          \
    __builtin_amdgcn_global_load_lds(                                                \
        (const __attribute__((address_space(1))) void*)(SRC),                        \
        (__attribute__((address_space(3))) void*)(DST), 16, 0, 0)

// ---------------------------------------------------------------------------
// Normalize centers, write fp16 transposed: cnT[j][d] = fc[d][j]/||fc[:,j]||
// ---------------------------------------------------------------------------
__global__ __launch_bounds__(256) void knorm(const float* __restrict__ fc,
                                             _Float16* __restrict__ cnT) {
    const int t = threadIdx.x;
    const int lane = t & 63;
    const int wid = t >> 6;
    const int c = lane & 15;
    const int q = lane >> 4;
    const int j = blockIdx.x * 64 + wid * 16 + c;

    float v[32];
    const float* p = fc + (size_t)(q * 32) * SUMK + j;
    float ss = 0.f;
#pragma unroll
    for (int i = 0; i < 32; ++i) {
        v[i] = p[(size_t)i * SUMK];
        ss = fmaf(v[i], v[i], ss);
    }
    ss += __shfl_xor(ss, 16);
    ss += __shfl_xor(ss, 32);
    float rn = 1.0f / sqrtf(ss);

    _Float16* w = cnT + (size_t)j * DIM + q * 32;
#pragma unroll
    for (int s = 0; s < 4; ++s) {
        half8 h;
#pragma unroll
        for (int k = 0; k < 8; ++k) h[k] = (_Float16)(v[s * 8 + k] * rn);
        *(half8*)(w + s * 8) = h;
    }
}

// ---------------------------------------------------------------------------
// kbig: ids 0..1023 = kmain (fused GEMM + fixed-shift softmax reduce),
//       ids 1024..3071 = kreg (center-pair regularizer) — backfills CUs.
// kmain: block = 4 waves x 32 rows = 128 rows; 512 cols (class-quarter).
// Centers staged to LDS (global_load_lds, fragment-major, conflict-free),
// 32-col chunks, triple buffer, one barrier per chunk.
// B-fragments pre-scaled by G2L so MFMA outputs s' = gamma*log2e*sim and
// epilogue is exp2 + add + fma per sim (no max tracking: |s'| <= ~14.5).
// ---------------------------------------------------------------------------
__global__ __launch_bounds__(256, 4) void kbig(const float* __restrict__ x,
                                               const _Float16* __restrict__ cnT,
                                               float* __restrict__ pw,
                                               float* __restrict__ reg_acc) {
    __shared__ _Float16 smem[3][2][4][64][8];   // 24 KB
    __shared__ float red[4];

    const int t = threadIdx.x;
    const int lane = t & 63;
    const int wid = t >> 6;
    const int m = lane & 15;
    const int kg = lane >> 4;
    const int id = blockIdx.x;

    if (id >= 1024) {
        // ---------------- kreg path ----------------
        const int rid = id - 1024;
        const int cls = rid >> 10;
        const int ti = (rid >> 5) & 31;
        const int tj = rid & 31;
        if (tj < ti) return;

        const int i0 = cls * KCLS + ti * 64 + wid * 16;
        const int jb = cls * KCLS + tj * 64;

        const _Float16* aip = cnT + (size_t)(i0 + m) * DIM + kg * 8;
        half8 af[4];
#pragma unroll
        for (int tt = 0; tt < 4; ++tt) af[tt] = *(const half8*)(aip + tt * 32);

        half8 bf[16];
#pragma unroll
        for (int fj = 0; fj < 4; ++fj) {
            const _Float16* bjp = cnT + (size_t)(jb + fj * 16 + m) * DIM + kg * 8;
#pragma unroll
            for (int tt = 0; tt < 4; ++tt) bf[fj * 4 + tt] = *(const half8*)(bjp + tt * 32);
        }

        float local = 0.f;
#pragma unroll
        for (int fj = 0; fj < 4; ++fj) {
            f32x4 cc = {0.f, 0.f, 0.f, 0.f};
#pragma unroll
            for (int tt = 0; tt < 4; ++tt)
                cc = __builtin_amdgcn_mfma_f32_16x16x32_f16(af[tt], bf[fj * 4 + tt], cc, 0, 0, 0);
            int gj = jb + fj * 16 + m;
#pragma unroll
            for (int r = 0; r < 4; ++r) {
                int gi = i0 + kg * 4 + r;
                if (gi < gj)
                    local += sqrtf(fmaxf(2.0f + 1e-5f - 2.f * cc[r], 0.f));
            }
        }
#pragma unroll
        for (int off = 1; off < 64; off <<= 1) local += __shfl_xor(local, off);
        if (lane == 0) red[wid] = local;
        __syncthreads();
        if (t == 0) atomicAdd(reg_acc, (red[0] + red[1]) + (red[2] + red[3]));
        return;
    }

    // ---------------- kmain path ----------------
    const int cls = (id >> 7) & 1;
    const int qz = id >> 8;
    const int r0 = (id & 127) * 128 + wid * 32;

    // stage assignment: wave wid stages fragment-slices q = wid*2, wid*2+1
    const int q0 = wid * 2, q1 = wid * 2 + 1;
    const int cf0 = q0 >> 2, tt0 = q0 & 3;
    const int cf1 = q1 >> 2, tt1 = q1 & 3;
    const int colbase = cls * KCLS + qz * 512;
    const _Float16* s0 = cnT + (size_t)(colbase + cf0 * 16 + m) * DIM + tt0 * 32 + kg * 8;
    const _Float16* s1 = cnT + (size_t)(colbase + cf1 * 16 + m) * DIM + tt1 * 32 + kg * 8;
    const size_t CSTEP = (size_t)32 * DIM;

#define STAGE(CH, BUF)                                                    \
    do {                                                                  \
        GLOAD_LDS(s0 + (size_t)(CH) * CSTEP, &smem[BUF][cf0][tt0][0][0]); \
        GLOAD_LDS(s1 + (size_t)(CH) * CSTEP, &smem[BUF][cf1][tt1][0][0]); \
    } while (0)

    STAGE(0, 0);
    STAGE(1, 1);

    // ---- load + normalize 2 x-rows; scale by G2L into B fragments ----
    half8 b0[4], b1[4];
#define LOADX(ROW, BF)                                                        \
    do {                                                                      \
        const float* xp = x + (size_t)(ROW)*DIM + kg * 8;                     \
        float xr[4][8];                                                       \
        float ss = 0.f;                                                       \
        _Pragma("unroll") for (int tt = 0; tt < 4; ++tt) {                    \
            float4 f0 = *(const float4*)(xp + tt * 32);                       \
            float4 f1 = *(const float4*)(xp + tt * 32 + 4);                   \
            xr[tt][0] = f0.x; xr[tt][1] = f0.y; xr[tt][2] = f0.z;             \
            xr[tt][3] = f0.w; xr[tt][4] = f1.x; xr[tt][5] = f1.y;             \
            xr[tt][6] = f1.z; xr[tt][7] = f1.w;                               \
            _Pragma("unroll") for (int qq = 0; qq < 8; ++qq)                  \
                ss = fmaf(xr[tt][qq], xr[tt][qq], ss);                        \
        }                                                                     \
        ss += __shfl_xor(ss, 16);                                             \
        ss += __shfl_xor(ss, 32);                                             \
        float rn = G2L / sqrtf(ss);                                           \
        _Pragma("unroll") for (int tt = 0; tt < 4; ++tt)                      \
            _Pragma("unroll") for (int qq = 0; qq < 8; ++qq)                  \
                BF[tt][qq] = (_Float16)(xr[tt][qq] * rn);                     \
    } while (0)

    LOADX(r0 + m, b0);
    LOADX(r0 + 16 + m, b1);
#undef LOADX

    float rz0 = 0.f, rw0 = 0.f, rz1 = 0.f, rw1 = 0.f;

#define EPI(C, RZ, RW)                                                        \
    do {                                                                      \
        float e0 = EXP2(C[0]);                                                \
        float e1 = EXP2(C[1]);                                                \
        float e2 = EXP2(C[2]);                                                \
        float e3 = EXP2(C[3]);                                                \
        RZ += (e0 + e1) + (e2 + e3);                                          \
        RW += fmaf(e0, C[0], e1 * C[1]) + fmaf(e2, C[2], e3 * C[3]);          \
    } while (0)

    for (int ch = 0; ch < 16; ++ch) {
        __syncthreads();                         // buf[ch%3] staged & visible
        if (ch + 2 < 16) STAGE(ch + 2, (ch + 2) % 3);
        const int b = ch % 3;
#pragma unroll
        for (int cf = 0; cf < 2; ++cf) {
            half8 a0 = *(const half8*)&smem[b][cf][0][lane][0];
            half8 a1 = *(const half8*)&smem[b][cf][1][lane][0];
            half8 a2 = *(const half8*)&smem[b][cf][2][lane][0];
            half8 a3 = *(const half8*)&smem[b][cf][3][lane][0];
            f32x4 c0 = {0.f, 0.f, 0.f, 0.f}, c1 = {0.f, 0.f, 0.f, 0.f};
            c0 = __builtin_amdgcn_mfma_f32_16x16x32_f16(a0, b0[0], c0, 0, 0, 0);
            c1 = __builtin_amdgcn_mfma_f32_16x16x32_f16(a0, b1[0], c1, 0, 0, 0);
            c0 = __builtin_amdgcn_mfma_f32_16x16x32_f16(a1, b0[1], c0, 0, 0, 0);
            c1 = __builtin_amdgcn_mfma_f32_16x16x32_f16(a1, b1[1], c1, 0, 0, 0);
            c0 = __builtin_amdgcn_mfma_f32_16x16x32_f16(a2, b0[2], c0, 0, 0, 0);
            c1 = __builtin_amdgcn_mfma_f32_16x16x32_f16(a2, b1[2], c1, 0, 0, 0);
            c0 = __builtin_amdgcn_mfma_f32_16x16x32_f16(a3, b0[3], c0, 0, 0, 0);
            c1 = __builtin_amdgcn_mfma_f32_16x16x32_f16(a3, b1[3], c1, 0, 0, 0);
            EPI(c0, rz0, rw0);
            EPI(c1, rz1, rw1);
        }
    }
#undef EPI
#undef STAGE

    // merge the 4 kg-groups (disjoint center subsets, plain sums)
    rz0 += __shfl_xor(rz0, 16); rz0 += __shfl_xor(rz0, 32);
    rw0 += __shfl_xor(rw0, 16); rw0 += __shfl_xor(rw0, 32);
    rz1 += __shfl_xor(rz1, 16); rz1 += __shfl_xor(rz1, 32);
    rw1 += __shfl_xor(rw1, 16); rw1 += __shfl_xor(rw1, 32);

    if (lane < 16) {
        const size_t base = (size_t)(cls * 4 + qz) * NB;
        const int rowA = r0 + m, rowB = r0 + 16 + m;
        pw[0 * CS + base + rowA] = rz0;
        pw[0 * CS + base + rowB] = rz1;
        pw[1 * CS + base + rowA] = rw0;
        pw[1 * CS + base + rowB] = rw1;
    }
}

// ---------------------------------------------------------------------------
// Merge column-quarter partials -> logits -> cross-entropy
// ---------------------------------------------------------------------------
__global__ __launch_bounds__(256) void kce(const float* __restrict__ pw,
                                           const int* __restrict__ tgt,
                                           float* __restrict__ out,
                                           float* __restrict__ ce_acc) {
    int i = blockIdx.x * 256 + threadIdx.x;
    float lg[2];
#pragma unroll
    for (int cls = 0; cls < 2; ++cls) {
        float z = 0.f, w = 0.f;
#pragma unroll
        for (int q = 0; q < 4; ++q) {
            const size_t base = (size_t)(cls * 4 + q) * NB + i;
            z += pw[0 * CS + base];
            w += pw[1 * CS + base];
        }
        lg[cls] = LA * (w / (z * G2L) - MARGIN);
        out[1 + 2 * i + cls] = lg[cls];
    }
    int tg = tgt[i];
    float mx = fmaxf(lg[0], lg[1]);
    float lse = mx + logf(expf(lg[0] - mx) + expf(lg[1] - mx));
    float ce = lse - (tg ? lg[1] : lg[0]);
#pragma unroll
    for (int off = 1; off < 64; off <<= 1) ce += __shfl_xor(ce, off);
    if ((threadIdx.x & 63) == 0) atomicAdd(ce_acc, ce);
}

// ---------------------------------------------------------------------------
// Finalize loss
// ---------------------------------------------------------------------------
__global__ void kfin(const float* __restrict__ accum, float* __restrict__ out) {
    out[0] = accum[0] / (float)NB + TAU * (accum[1] / NPAIRS2);
}

extern "C" void kernel_launch(void* const* d_in, const int* in_sizes, int n_in,
                              void* d_out, int out_size, void* d_ws, size_t ws_size,
                              hipStream_t stream) {
    const float* x  = (const float*)d_in[0];
    const int*   tg = (const int*)d_in[1];
    const float* fc = (const float*)d_in[2];
    float* out = (float*)d_out;
    float* ws  = (float*)d_ws;
    float* accum = ws;                            // [0]=ce sum, [1]=reg sum
    _Float16* cnT = (_Float16*)(ws + 16);         // [SUMK][DIM] fp16, 1 MB
    float* pw = (float*)(cnT + (size_t)SUMK * DIM);  // partials, 2*8*NB floats

    hipMemsetAsync(accum, 0, 64, stream);
    knorm<<<SUMK / 64, 256, 0, stream>>>(fc, cnT);
    kbig<<<1024 + 2048, 256, 0, stream>>>(x, cnT, pw, accum + 1);
    kce<<<NB / 256, 256, 0, stream>>>(pw, tg, out, accum);
    kfin<<<1, 1, 0, stream>>>(accum, out);
}

// Round 7
// 112.942 us; speedup vs baseline: 4.2957x; 1.0417x over previous
//
#include <hip/hip_runtime.h>
#include <math.h>

#define NB 16384
#define DIM 128
#define SUMK 4096
#define KCLS 2048

constexpr float LA = 20.0f;
constexpr float TAU = 0.2f;
constexpr float MARGIN = 0.01f;
constexpr float NPAIRS2 = 8384512.0f;          // 2048*2047*2
constexpr float G2L = 14.426950408889634f;     // GAMMA_INV * log2(e)
#define CS (8 * NB)                            // per-component stride in pw

typedef _Float16 half8 __attribute__((ext_vector_type(8)));
typedef float f32x4 __attribute__((ext_vector_type(4)));

#if __has_builtin(__builtin_amdgcn_exp2f)
#define EXP2(v) __builtin_amdgcn_exp2f(v)
#else
#define EXP2(v) exp2f(v)
#endif

// direct global->LDS DMA, 16B per lane; dst is wave-uniform base (+lane*16 in HW)
#define GLOAD_LDS(SRC, DST)                                                          \
    __builtin_amdgcn_global_load_lds(                                                \
        (const __attribute__((address_space(1))) void*)(SRC),                        \
        (__attribute__((address_space(3))) void*)(DST), 16, 0, 0)

// ---------------------------------------------------------------------------
// knorm: normalize centers -> fp16 transposed cnT[j][d].
// Fully coalesced: LDS-tiled transpose, 128 blocks x 32 columns.
// ---------------------------------------------------------------------------
__global__ __launch_bounds__(256) void knorm(const float* __restrict__ fc,
                                             _Float16* __restrict__ cnT) {
    __shared__ float tile[DIM][35];            // pad 35 (odd): 2-way max on phase2
    const int t = threadIdx.x;
    const int j0 = blockIdx.x * 32;

    // phase 1: coalesced read (128B/row-octet), 8 rows per iteration
    const int jr = t & 31;
    const int dr = t >> 5;
#pragma unroll
    for (int it = 0; it < 16; ++it) {
        int d = it * 8 + dr;
        tile[d][jr] = fc[(size_t)d * SUMK + j0 + jr];
    }
    __syncthreads();

    // phase 2: 8 threads per column, 16 dims each
    const int p = t & 7;
    const int j = t >> 3;
    float v[16];
    float ss = 0.f;
#pragma unroll
    for (int i = 0; i < 16; ++i) {
        v[i] = tile[p * 16 + i][j];
        ss = fmaf(v[i], v[i], ss);
    }
    ss += __shfl_xor(ss, 1);
    ss += __shfl_xor(ss, 2);
    ss += __shfl_xor(ss, 4);
    float rn = 1.0f / sqrtf(ss);

    _Float16* w = cnT + (size_t)(j0 + j) * DIM + p * 16;
    half8 h0, h1;
#pragma unroll
    for (int k = 0; k < 8; ++k) {
        h0[k] = (_Float16)(v[k] * rn);
        h1[k] = (_Float16)(v[8 + k] * rn);
    }
    *(half8*)w = h0;
    *(half8*)(w + 8) = h1;
}

// ---------------------------------------------------------------------------
// kbig: ids 0..1023 = fused GEMM + fixed-shift softmax reduce,
//       ids 1024..3071 = center-pair regularizer (backfills CUs).
// Main loop: counted-vmcnt pipeline (T3/T4): per chunk
//   s_waitcnt vmcnt(2)  -> own stage(ch) landed   (never 0 in-loop)
//   s_barrier           -> all waves' stage(ch) landed, prev reads done
//   STAGE(ch+2)         -> overwrite buf[(ch-1)%3], 2 chunks to complete
//   compute(ch)
// ---------------------------------------------------------------------------
__global__ __launch_bounds__(256, 4) void kbig(const float* __restrict__ x,
                                               const _Float16* __restrict__ cnT,
                                               float* __restrict__ pw,
                                               float* __restrict__ reg_acc) {
    __shared__ _Float16 smem[3][2][4][64][8];   // 24 KB
    __shared__ float red[4];

    const int t = threadIdx.x;
    const int lane = t & 63;
    const int wid = t >> 6;
    const int m = lane & 15;
    const int kg = lane >> 4;
    const int id = blockIdx.x;

    if (id >= 1024) {
        // ---------------- kreg path ----------------
        const int rid = id - 1024;
        const int cls = rid >> 10;
        const int ti = (rid >> 5) & 31;
        const int tj = rid & 31;
        if (tj < ti) return;

        const int i0 = cls * KCLS + ti * 64 + wid * 16;
        const int jb = cls * KCLS + tj * 64;

        const _Float16* aip = cnT + (size_t)(i0 + m) * DIM + kg * 8;
        half8 af[4];
#pragma unroll
        for (int tt = 0; tt < 4; ++tt) af[tt] = *(const half8*)(aip + tt * 32);

        half8 bf[16];
#pragma unroll
        for (int fj = 0; fj < 4; ++fj) {
            const _Float16* bjp = cnT + (size_t)(jb + fj * 16 + m) * DIM + kg * 8;
#pragma unroll
            for (int tt = 0; tt < 4; ++tt) bf[fj * 4 + tt] = *(const half8*)(bjp + tt * 32);
        }

        float local = 0.f;
#pragma unroll
        for (int fj = 0; fj < 4; ++fj) {
            f32x4 cc = {0.f, 0.f, 0.f, 0.f};
#pragma unroll
            for (int tt = 0; tt < 4; ++tt)
                cc = __builtin_amdgcn_mfma_f32_16x16x32_f16(af[tt], bf[fj * 4 + tt], cc, 0, 0, 0);
            int gj = jb + fj * 16 + m;
#pragma unroll
            for (int r = 0; r < 4; ++r) {
                int gi = i0 + kg * 4 + r;
                if (gi < gj)
                    local += sqrtf(fmaxf(2.0f + 1e-5f - 2.f * cc[r], 0.f));
            }
        }
#pragma unroll
        for (int off = 1; off < 64; off <<= 1) local += __shfl_xor(local, off);
        if (lane == 0) red[wid] = local;
        __syncthreads();
        if (t == 0) atomicAdd(reg_acc, (red[0] + red[1]) + (red[2] + red[3]));
        return;
    }

    // ---------------- kmain path ----------------
    const int cls = (id >> 7) & 1;
    const int qz = id >> 8;
    const int r0 = (id & 127) * 128 + wid * 32;

    // ---- load + normalize 2 x-rows FIRST (so x-waits don't drain stages) ----
    half8 b0[4], b1[4];
#define LOADX(ROW, BF)                                                        \
    do {                                                                      \
        const float* xp = x + (size_t)(ROW)*DIM + kg * 8;                     \
        float xr[4][8];                                                       \
        float ss = 0.f;                                                       \
        _Pragma("unroll") for (int tt = 0; tt < 4; ++tt) {                    \
            float4 f0 = *(const float4*)(xp + tt * 32);                       \
            float4 f1 = *(const float4*)(xp + tt * 32 + 4);                   \
            xr[tt][0] = f0.x; xr[tt][1] = f0.y; xr[tt][2] = f0.z;             \
            xr[tt][3] = f0.w; xr[tt][4] = f1.x; xr[tt][5] = f1.y;             \
            xr[tt][6] = f1.z; xr[tt][7] = f1.w;                               \
            _Pragma("unroll") for (int qq = 0; qq < 8; ++qq)                  \
                ss = fmaf(xr[tt][qq], xr[tt][qq], ss);                        \
        }                                                                     \
        ss += __shfl_xor(ss, 16);                                             \
        ss += __shfl_xor(ss, 32);                                             \
        float rn = G2L / sqrtf(ss);                                           \
        _Pragma("unroll") for (int tt = 0; tt < 4; ++tt)                      \
            _Pragma("unroll") for (int qq = 0; qq < 8; ++qq)                  \
                BF[tt][qq] = (_Float16)(xr[tt][qq] * rn);                     \
    } while (0)

    LOADX(r0 + m, b0);
    LOADX(r0 + 16 + m, b1);
#undef LOADX

    // stage assignment: wave wid stages fragment-slices q = wid*2, wid*2+1
    const int q0 = wid * 2, q1 = wid * 2 + 1;
    const int cf0 = q0 >> 2, tt0 = q0 & 3;
    const int cf1 = q1 >> 2, tt1 = q1 & 3;
    const int colbase = cls * KCLS + qz * 512;
    const _Float16* s0 = cnT + (size_t)(colbase + cf0 * 16 + m) * DIM + tt0 * 32 + kg * 8;
    const _Float16* s1 = cnT + (size_t)(colbase + cf1 * 16 + m) * DIM + tt1 * 32 + kg * 8;
    const size_t CSTEP = (size_t)32 * DIM;

#define STAGE(CH, BUF)                                                    \
    do {                                                                  \
        GLOAD_LDS(s0 + (size_t)(CH) * CSTEP, &smem[BUF][cf0][tt0][0][0]); \
        GLOAD_LDS(s1 + (size_t)(CH) * CSTEP, &smem[BUF][cf1][tt1][0][0]); \
    } while (0)

    float rz0 = 0.f, rw0 = 0.f, rz1 = 0.f, rw1 = 0.f;

#define EPI(C, RZ, RW)                                                        \
    do {                                                                      \
        float e0 = EXP2(C[0]);                                                \
        float e1 = EXP2(C[1]);                                                \
        float e2 = EXP2(C[2]);                                                \
        float e3 = EXP2(C[3]);                                                \
        RZ += (e0 + e1) + (e2 + e3);                                          \
        RW += fmaf(e0, C[0], e1 * C[1]) + fmaf(e2, C[2], e3 * C[3]);          \
    } while (0)

#define COMPUTE(B)                                                            \
    do {                                                                      \
        _Pragma("unroll") for (int cf = 0; cf < 2; ++cf) {                    \
            half8 a0 = *(const half8*)&smem[B][cf][0][lane][0];               \
            half8 a1 = *(const half8*)&smem[B][cf][1][lane][0];               \
            half8 a2 = *(const half8*)&smem[B][cf][2][lane][0];               \
            half8 a3 = *(const half8*)&smem[B][cf][3][lane][0];               \
            f32x4 c0 = {0.f, 0.f, 0.f, 0.f}, c1 = {0.f, 0.f, 0.f, 0.f};      \
            c0 = __builtin_amdgcn_mfma_f32_16x16x32_f16(a0, b0[0], c0, 0, 0, 0); \
            c1 = __builtin_amdgcn_mfma_f32_16x16x32_f16(a0, b1[0], c1, 0, 0, 0); \
            c0 = __builtin_amdgcn_mfma_f32_16x16x32_f16(a1, b0[1], c0, 0, 0, 0); \
            c1 = __builtin_amdgcn_mfma_f32_16x16x32_f16(a1, b1[1], c1, 0, 0, 0); \
            c0 = __builtin_amdgcn_mfma_f32_16x16x32_f16(a2, b0[2], c0, 0, 0, 0); \
            c1 = __builtin_amdgcn_mfma_f32_16x16x32_f16(a2, b1[2], c1, 0, 0, 0); \
            c0 = __builtin_amdgcn_mfma_f32_16x16x32_f16(a3, b0[3], c0, 0, 0, 0); \
            c1 = __builtin_amdgcn_mfma_f32_16x16x32_f16(a3, b1[3], c1, 0, 0, 0); \
            EPI(c0, rz0, rw0);                                                \
            EPI(c1, rz1, rw1);                                                \
        }                                                                     \
    } while (0)

    STAGE(0, 0);
    STAGE(1, 1);

    for (int ch = 0; ch < 15; ++ch) {
        asm volatile("s_waitcnt vmcnt(2)" ::: "memory");  // own stage(ch) landed
        __builtin_amdgcn_s_barrier();                     // all stage(ch) landed; prev reads done
        if (ch < 14) STAGE(ch + 2, (ch + 2) % 3);         // overwrite buf[(ch-1)%3]
        COMPUTE(ch % 3);
    }
    asm volatile("s_waitcnt vmcnt(0)" ::: "memory");      // tail: stage(15)
    __builtin_amdgcn_s_barrier();
    COMPUTE(0);                                           // 15 % 3
#undef COMPUTE
#undef EPI
#undef STAGE

    // merge the 4 kg-groups (disjoint center subsets, plain sums)
    rz0 += __shfl_xor(rz0, 16); rz0 += __shfl_xor(rz0, 32);
    rw0 += __shfl_xor(rw0, 16); rw0 += __shfl_xor(rw0, 32);
    rz1 += __shfl_xor(rz1, 16); rz1 += __shfl_xor(rz1, 32);
    rw1 += __shfl_xor(rw1, 16); rw1 += __shfl_xor(rw1, 32);

    if (lane < 16) {
        const size_t base = (size_t)(cls * 4 + qz) * NB;
        const int rowA = r0 + m, rowB = r0 + 16 + m;
        pw[0 * CS + base + rowA] = rz0;
        pw[0 * CS + base + rowB] = rz1;
        pw[1 * CS + base + rowA] = rw0;
        pw[1 * CS + base + rowB] = rw1;
    }
}

// ---------------------------------------------------------------------------
// kce: merge partials -> logits -> cross-entropy; last block finalizes loss.
// ---------------------------------------------------------------------------
__global__ __launch_bounds__(256) void kce(const float* __restrict__ pw,
                                           const int* __restrict__ tgt,
                                           float* __restrict__ out,
                                           float* __restrict__ accum) {
    __shared__ float red2[4];
    const int t = threadIdx.x;
    int i = blockIdx.x * 256 + t;
    float lg[2];
#pragma unroll
    for (int cls = 0; cls < 2; ++cls) {
        float z = 0.f, w = 0.f;
#pragma unroll
        for (int q = 0; q < 4; ++q) {
            const size_t base = (size_t)(cls * 4 + q) * NB + i;
            z += pw[0 * CS + base];
            w += pw[1 * CS + base];
        }
        lg[cls] = LA * (w / (z * G2L) - MARGIN);
        out[1 + 2 * i + cls] = lg[cls];
    }
    int tg = tgt[i];
    float mx = fmaxf(lg[0], lg[1]);
    float lse = mx + logf(expf(lg[0] - mx) + expf(lg[1] - mx));
    float ce = lse - (tg ? lg[1] : lg[0]);
#pragma unroll
    for (int off = 1; off < 64; off <<= 1) ce += __shfl_xor(ce, off);
    if ((t & 63) == 0) red2[t >> 6] = ce;
    __syncthreads();
    if (t == 0) {
        atomicAdd(&accum[0], (red2[0] + red2[1]) + (red2[2] + red2[3]));
        __threadfence();
        unsigned old = atomicAdd((unsigned*)&accum[2], 1u);
        if (old == (unsigned)(NB / 256 - 1)) {
            float ce_tot = atomicAdd(&accum[0], 0.0f);   // atomic read, all adds visible
            float reg    = atomicAdd(&accum[1], 0.0f);   // kbig finished (stream order)
            out[0] = ce_tot / (float)NB + TAU * (reg / NPAIRS2);
        }
    }
}

extern "C" void kernel_launch(void* const* d_in, const int* in_sizes, int n_in,
                              void* d_out, int out_size, void* d_ws, size_t ws_size,
                              hipStream_t stream) {
    const float* x  = (const float*)d_in[0];
    const int*   tg = (const int*)d_in[1];
    const float* fc = (const float*)d_in[2];
    float* out = (float*)d_out;
    float* ws  = (float*)d_ws;
    float* accum = ws;                            // [0]=ce, [1]=reg, [2]=counter
    _Float16* cnT = (_Float16*)(ws + 16);         // [SUMK][DIM] fp16, 1 MB
    float* pw = (float*)(cnT + (size_t)SUMK * DIM);  // partials, 2*8*NB floats

    hipMemsetAsync(accum, 0, 64, stream);
    knorm<<<SUMK / 32, 256, 0, stream>>>(fc, cnT);
    kbig<<<1024 + 2048, 256, 0, stream>>>(x, cnT, pw, accum + 1);
    kce<<<NB / 256, 256, 0, stream>>>(pw, tg, out, accum);
}